// Round 2
// baseline (703.404 us; speedup 1.0000x reference)
//
#include <hip/hip_runtime.h>
#include <stdint.h>

typedef unsigned int u32;
typedef unsigned long long u64;
typedef unsigned short u16;
typedef unsigned char u8;
typedef int intx4 __attribute__((ext_vector_type(4)));
typedef int intx8 __attribute__((ext_vector_type(8)));
typedef float floatx4 __attribute__((ext_vector_type(4)));

#define BATCH 4096
#define IN    2048
#define HID   8192
#define NCLS  1000

// ---------- ws layout (bytes) ----------
#define OFF_ROWKEY 0u                       // u64[4096]      32 KB (fallback)
#define OFF_TOPK   32768u                   // u32[4096*512]   8 MB
#define OFF_X8     8421376u                 // fp8 x           8 MB
#define OFF_WK8    16809984u                // fp8 Wk         16 MB
#define OFF_WGT    33587200u                // fp32 Wg^T   31.25 MB
#define TOTAL_FULL 66355200ull

// ---------- helpers ----------
__device__ __forceinline__ u32 fkey(float f) {          // monotonic float->u32
    u32 u = __float_as_uint(f);
    return (u & 0x80000000u) ? ~u : (u | 0x80000000u);
}
__device__ __forceinline__ float unfkey(u32 k) {
    return __uint_as_float((k & 0x80000000u) ? (k ^ 0x80000000u) : ~k);
}
__device__ __forceinline__ void ce32(u32& a, u32& b) {  // desc compare-exchange (2 ops)
    u32 mx = a > b ? a : b;
    u32 mn = a > b ? b : a;
    a = mx; b = mn;
}

// ---------- prep: convert x & Wk to fp8 e4m3 (unit scale), transpose Wg ----------
__global__ __launch_bounds__(256) void prep_kernel(
    const float* __restrict__ x, const float* __restrict__ Wk,
    const float* __restrict__ Wg,
    u8* __restrict__ x8, u8* __restrict__ wk8, float* __restrict__ WgT)
{
    __shared__ float t[32][33];
    const int bid = blockIdx.x;
    if (bid < 1024) {
        const int gid = bid * 256 + threadIdx.x;
        const int NSX = BATCH * IN / 16;          // 524288
        const int NS  = NSX + HID * IN / 16;      // 1572864
        for (int s = gid; s < NS; s += 1024 * 256) {
            const float4* src; u8* dst;
            if (s < NSX) { src = (const float4*)x + (size_t)s * 4;  dst = x8  + (size_t)s * 16; }
            else { int u = s - NSX; src = (const float4*)Wk + (size_t)u * 4; dst = wk8 + (size_t)u * 16; }
            uint4 o;
            float4 f;
            int p;
            f = src[0];
            p = __builtin_amdgcn_cvt_pk_fp8_f32(f.x, f.y, 0, false);
            p = __builtin_amdgcn_cvt_pk_fp8_f32(f.z, f.w, p, true);  o.x = (u32)p;
            f = src[1];
            p = __builtin_amdgcn_cvt_pk_fp8_f32(f.x, f.y, 0, false);
            p = __builtin_amdgcn_cvt_pk_fp8_f32(f.z, f.w, p, true);  o.y = (u32)p;
            f = src[2];
            p = __builtin_amdgcn_cvt_pk_fp8_f32(f.x, f.y, 0, false);
            p = __builtin_amdgcn_cvt_pk_fp8_f32(f.z, f.w, p, true);  o.z = (u32)p;
            f = src[3];
            p = __builtin_amdgcn_cvt_pk_fp8_f32(f.x, f.y, 0, false);
            p = __builtin_amdgcn_cvt_pk_fp8_f32(f.z, f.w, p, true);  o.w = (u32)p;
            *(uint4*)dst = o;
        }
    } else {
        const int tb = bid - 1024;
        const int bx = (tb & 255) * 32;   // HID
        const int by = (tb >> 8) * 32;    // NCLS
        const int tx = threadIdx.x & 31, ty = threadIdx.x >> 5;  // ty 0..7
        #pragma unroll
        for (int i = 0; i < 32; i += 8) {
            int c = by + ty + i;
            t[ty + i][tx] = (c < NCLS) ? Wg[(size_t)c * HID + bx + tx] : 0.f;
        }
        __syncthreads();
        #pragma unroll
        for (int i = 0; i < 32; i += 8) {
            int c = by + tx;
            if (c < NCLS) WgT[(size_t)(bx + ty + i) * NCLS + by + tx] = t[tx][ty + i];
        }
    }
}

// ---------- fp8 MFMA GEMM, 8-wave 128x256 tile, ring-3, LDS-pipe pipelined ----------
// Round-2 diagnosis: kernel is LDS-read-bound (128KB/CU/K-tile reads > 1106cy
// MFMA) with 4-way bank conflicts (+4cy/b128, 8.4M extra cy) and read/MFMA
// pipes SERIALIZED by the lgkmcnt(0)-before-MFMA structure. Fixes (math
// bit-identical; fragments/MFMA order/epilogue unchanged):
//  1. 8-slot 16B XOR swizzle: physical slot p of row r holds logical 16B chunk
//     p^(r&7). Fragment = two ds_read_b128 at slots (2q+h)^(m&7) -> 64 lane
//     addrs spread all 32 banks (2-way max = free). Staging keeps full row
//     coalescing (permutation stays inside each 128B row).
//  2. Software-pipelined fragment reads: kt+1's 16 ds_reads issued DURING kt's
//     MFMA clusters; counted lgkmcnt(4)/(8) ladder (never 0 mid-loop). Safe:
//     buffer kt+1 proven complete (vmcnt(0)+barrier) at kt-1's end.
//  3. ONE barrier per K-tile; end-of-tile vmcnt(0) drains stages issued a full
//     K-tile (~1500cy) earlier against L2-resident data -> ~free.
#define STAGE(gsrc, ldsoff) \
    __builtin_amdgcn_global_load_lds((const __attribute__((address_space(1))) u32*)(gsrc), \
        (__attribute__((address_space(3))) u32*)&LDS[ldsoff], 16, 0, 0)

#define RD_A(dst, base) { _Pragma("unroll") for (int i_ = 0; i_ < 4; i_++) { \
    intx4 lo_ = *(const intx4*)&LDS[(base) + aAddr[i_] + sLo]; \
    intx4 hi_ = *(const intx4*)&LDS[(base) + aAddr[i_] + sHi]; \
    dst[i_] = __builtin_shufflevector(lo_, hi_, 0,1,2,3,4,5,6,7); } }

#define RD_B01(dst, base) { _Pragma("unroll") for (int j_ = 0; j_ < 2; j_++) { \
    intx4 lo_ = *(const intx4*)&LDS[(base) + bAddr[j_] + sLo]; \
    intx4 hi_ = *(const intx4*)&LDS[(base) + bAddr[j_] + sHi]; \
    dst[j_] = __builtin_shufflevector(lo_, hi_, 0,1,2,3,4,5,6,7); } }

#define RD_B23(dst, base) { _Pragma("unroll") for (int j_ = 2; j_ < 4; j_++) { \
    intx4 lo_ = *(const intx4*)&LDS[(base) + bAddr[j_] + sLo]; \
    intx4 hi_ = *(const intx4*)&LDS[(base) + bAddr[j_] + sHi]; \
    dst[j_] = __builtin_shufflevector(lo_, hi_, 0,1,2,3,4,5,6,7); } }

#define MFMA_J(afX, bfX, J) { _Pragma("unroll") for (int i_ = 0; i_ < 4; i_++) \
    acc[i_][J] = __builtin_amdgcn_mfma_scale_f32_16x16x128_f8f6f4( \
        afX[i_], bfX[J], acc[i_][J], 0, 0, 0, 0x7F, 0, 0x7F); }

// One K-tile. Entry invariant (post-barrier): lgkm out = 16 (KT's reads, order
// af8|b01_4|b23_4), vm out = 0, buffers KT and KT+1 complete & visible.
#define KT_BODY(KT, afC, bfC, afN, bfN)                                        \
{                                                                              \
    const u32 nb_   = (u32)(((KT) + 1) % 3) * 49152u;                          \
    const u32 sbuf_ = (u32)(((KT) + 2) % 3) * 49152u;                          \
    if ((KT) < 14) {                                                           \
        const size_t ko_ = (size_t)((KT) + 2) * 128;                           \
        STAGE(gxa + ko_,                     sbuf_          + ldst);           \
        STAGE(gxa +  64 * (size_t)IN + ko_,  sbuf_ + 8192u  + ldst);           \
        STAGE(gwb + ko_,                     sbuf_ + 16384u + ldst);           \
        STAGE(gwb +  64 * (size_t)IN + ko_,  sbuf_ + 24576u + ldst);           \
        STAGE(gwb + 128 * (size_t)IN + ko_,  sbuf_ + 32768u + ldst);           \
        STAGE(gwb + 192 * (size_t)IN + ko_,  sbuf_ + 40960u + ldst);           \
    }                                                                          \
    asm volatile("s_waitcnt lgkmcnt(4)" ::: "memory");  /* af+b01 ready */     \
    __builtin_amdgcn_sched_barrier(0);                                         \
    if ((KT) < 15) { RD_A(afN, nb_) }                   /* +8, out=12 */       \
    asm volatile("" ::: "memory");                                             \
    __builtin_amdgcn_s_setprio(1);                                             \
    MFMA_J(afC, bfC, 0)                                                        \
    MFMA_J(afC, bfC, 1)                                                        \
    __builtin_amdgcn_s_setprio(0);                                             \
    if ((KT) < 15) { asm volatile("s_waitcnt lgkmcnt(8)" ::: "memory"); }      \
    else           { asm volatile("s_waitcnt lgkmcnt(0)" ::: "memory"); }      \
    __builtin_amdgcn_sched_barrier(0);                                         \
    if ((KT) < 15) { RD_B01(bfN, nb_) }                 /* +4, out=12 */       \
    asm volatile("" ::: "memory");                                             \
    __builtin_amdgcn_s_setprio(1);                                             \
    MFMA_J(afC, bfC, 2)                                                        \
    MFMA_J(afC, bfC, 3)                                                        \
    __builtin_amdgcn_s_setprio(0);                                             \
    if ((KT) < 15) { RD_B23(bfN, nb_) }                 /* +4, out=16 */       \
    if ((KT) < 15) {                                                           \
        asm volatile("s_waitcnt vmcnt(0)" ::: "memory"); /* KT+2 staged */     \
        __builtin_amdgcn_s_barrier();                                          \
        asm volatile("" ::: "memory");                                         \
    }                                                                          \
}

__global__ __launch_bounds__(512) void mfma_fp8_gemm_kernel(
    const u8* __restrict__ x8, const u8* __restrict__ wk8,
    u32* __restrict__ topk)
{
    __shared__ __align__(16) u8 LDS[3 * 49152];   // 144 KB ring of 3

    const int tid  = threadIdx.x;
    const int lane = tid & 63;
    const int w    = tid >> 6;                    // 0..7
    const int bm   = blockIdx.y * 128;
    const int bn   = blockIdx.x * 256;
    const int wrow = (w >> 2) * 64;               // 2 M-wave-groups
    const int wcol = (w & 3) * 64;                // 4 N-wave-groups
    const int m = lane & 15, q = lane >> 4;

    floatx4 acc[4][4];
    #pragma unroll
    for (int i = 0; i < 4; i++)
        #pragma unroll
        for (int j = 0; j < 4; j++)
            acc[i][j] = (floatx4){0.f, 0.f, 0.f, 0.f};

    // staging: 512 threads cover 64 rows x 128B per 8KB region; LDS physical
    // slot p = tid&7 of row srow holds logical chunk p ^ (srow&7)
    const int srow = tid >> 3;                                        // 0..63
    const int soff = ((tid & 7) ^ (srow & 7)) * 16;
    const u8* gxa = x8  + (size_t)(bm + srow) * IN + soff;
    const u8* gwb = wk8 + (size_t)(bn + srow) * IN + soff;
    const u32 ldst = (u32)tid * 16;

    // fragment read: logical chunk (2q+h) of row r sits at slot (2q+h)^(r&7)
    const u32 sLo = ((((u32)q << 1) ^ ((u32)m & 7u))) * 16u;
    const u32 sHi = sLo ^ 16u;
    u32 aAddr[4], bAddr[4];
    #pragma unroll
    for (int i = 0; i < 4; i++) aAddr[i] = (u32)(wrow + i * 16 + m) * 128u;
    #pragma unroll
    for (int j = 0; j < 4; j++) bAddr[j] = 16384u + (u32)(wcol + j * 16 + m) * 128u;

    intx8 afA[4], bfA[4], afB[4], bfB[4];

    // ---- prologue: stage kt0->buf0, kt1->buf1; prove; read kt0 frags ----
    STAGE(gxa,                            0u         + ldst);
    STAGE(gxa +  64 * (size_t)IN,         8192u      + ldst);
    STAGE(gwb,                            16384u     + ldst);
    STAGE(gwb +  64 * (size_t)IN,         24576u     + ldst);
    STAGE(gwb + 128 * (size_t)IN,         32768u     + ldst);
    STAGE(gwb + 192 * (size_t)IN,         40960u     + ldst);
    STAGE(gxa + 128,                      49152u          + ldst);
    STAGE(gxa +  64 * (size_t)IN + 128,   49152u + 8192u  + ldst);
    STAGE(gwb + 128,                      49152u + 16384u + ldst);
    STAGE(gwb +  64 * (size_t)IN + 128,   49152u + 24576u + ldst);
    STAGE(gwb + 128 * (size_t)IN + 128,   49152u + 32768u + ldst);
    STAGE(gwb + 192 * (size_t)IN + 128,   49152u + 40960u + ldst);
    asm volatile("s_waitcnt vmcnt(0)" ::: "memory");   // buf0+buf1 landed
    __builtin_amdgcn_s_barrier();                      // ...cross-wave
    asm volatile("" ::: "memory");
    RD_A(afA, 0u)                                      // out=8
    asm volatile("" ::: "memory");
    RD_B01(bfA, 0u)                                    // out=12
    asm volatile("" ::: "memory");
    RD_B23(bfA, 0u)                                    // out=16
    asm volatile("" ::: "memory");

    #pragma unroll
    for (int kp = 0; kp < 8; ++kp) {
        KT_BODY(kp * 2,     afA, bfA, afB, bfB)
        KT_BODY(kp * 2 + 1, afB, bfB, afA, bfA)
    }

    // epilogue: per-row top-4 (u32 keys) over this wave's 64 columns
    const int group = blockIdx.x * 4 + (w & 3);   // 64-col group id, 0..127
    #pragma unroll
    for (int i = 0; i < 4; i++) {
        #pragma unroll
        for (int r = 0; r < 4; r++) {
            u32 k0 = (fkey(acc[i][0][r]) & 0xFFFFFFC0u) | (0u << 4) | (u32)m;
            u32 k1 = (fkey(acc[i][1][r]) & 0xFFFFFFC0u) | (1u << 4) | (u32)m;
            u32 k2 = (fkey(acc[i][2][r]) & 0xFFFFFFC0u) | (2u << 4) | (u32)m;
            u32 k3 = (fkey(acc[i][3][r]) & 0xFFFFFFC0u) | (3u << 4) | (u32)m;
            // sort 4 desc
            ce32(k0, k1); ce32(k2, k3); ce32(k0, k2); ce32(k1, k3); ce32(k1, k2);
            // butterfly top-4 merge over the 16 lanes sharing this row
            #pragma unroll
            for (int off = 1; off < 16; off <<= 1) {
                u32 b0 = __shfl_xor(k0, off, 64);
                u32 b1 = __shfl_xor(k1, off, 64);
                u32 b2 = __shfl_xor(k2, off, 64);
                u32 b3 = __shfl_xor(k3, off, 64);
                u32 t0 = k0 > b3 ? k0 : b3;    // bitonic keep-max
                u32 t1 = k1 > b2 ? k1 : b2;
                u32 t2 = k2 > b1 ? k2 : b1;
                u32 t3 = k3 > b0 ? k3 : b0;
                ce32(t0, t2); ce32(t1, t3); ce32(t0, t1); ce32(t2, t3);
                k0 = t0; k1 = t1; k2 = t2; k3 = t3;
            }
            if (m == 0) {
                const int grow = bm + wrow + i * 16 + q * 4 + r;
                uint4 v; v.x = k0; v.y = k1; v.z = k2; v.w = k3;
                *(uint4*)&topk[(size_t)grow * 512 + group * 4] = v;
            }
        }
    }
}

// ---------- scan: one WAVE per row; ballot compaction; exact rescore; gather ----------
__global__ __launch_bounds__(256) void scan_kernel(
    const u32* __restrict__ topk,
    const float* __restrict__ x, const float* __restrict__ Wk,
    const float* __restrict__ WgT, float* __restrict__ out)
{
    __shared__ u16 cand[4][48];
    const int wv   = threadIdx.x >> 6;
    const int lane = threadIdx.x & 63;
    const int row  = blockIdx.x * 4 + wv;

    const uint4* tp = (const uint4*)(topk + (size_t)row * 512);
    uint4 v0 = tp[lane];        // group = lane
    uint4 v1 = tp[lane + 64];   // group = lane + 64

    // row max (u32 keys are value-ordered; id bits only break near-ties)
    u32 mx = v0.x > v1.x ? v0.x : v1.x;   // slot 0 of each uint4 is its group's max
    #pragma unroll
    for (int off = 1; off < 64; off <<= 1) {
        u32 o = __shfl_xor(mx, off, 64);
        if (o > mx) mx = o;
    }
    const float thr = unfkey(mx & 0xFFFFFFC0u) - 12.0f;

    // ballot-compact in-window candidates into per-wave LDS (no atomics)
    int base = 0;
    const u32 ks[8] = {v0.x, v0.y, v0.z, v0.w, v1.x, v1.y, v1.z, v1.w};
    #pragma unroll
    for (int s = 0; s < 8; s++) {
        const int group = (s < 4) ? lane : (lane + 64);
        const u32 key = ks[s];
        const bool in = unfkey(key & 0xFFFFFFC0u) >= thr;
        const u64 msk = __ballot(in);
        if (in) {
            int rnk = base + __popcll(msk & ((1ull << lane) - 1ull));
            if (rnk < 48)
                cand[wv][rnk] = (u16)(group * 64 + (int)((key >> 4) & 3u) * 16 + (int)(key & 15u));
        }
        base += __popcll(msk);
    }
    const int n = min(base, 48);
    __builtin_amdgcn_wave_barrier();   // keep compiler from sinking LDS reads above writes

    int col;
    if (n <= 1) {
        col = cand[wv][0];   // the max itself is always in-window
    } else {
        // exact fp32 rescore, whole wave per candidate
        const float4* xr = (const float4*)(x + (size_t)row * IN);
        float4 a[8];
        #pragma unroll
        for (int p = 0; p < 8; p++) a[p] = xr[p * 64 + lane];
        u64 best = 0ull;
        for (int c = 0; c < n; c++) {
            const int h = cand[wv][c];
            const float4* wr = (const float4*)(Wk + (size_t)h * IN);
            float s = 0.f;
            #pragma unroll
            for (int p = 0; p < 8; p++) {
                float4 b = wr[p * 64 + lane];
                s += a[p].x * b.x + a[p].y * b.y + a[p].z * b.z + a[p].w * b.w;
            }
            #pragma unroll
            for (int off = 1; off < 64; off <<= 1) s += __shfl_xor(s, off, 64);
            // s identical on all lanes; track best on all lanes (no broadcast needed)
            u64 key = ((u64)fkey(s) << 32) | (u64)(0x1FFFu - (u32)h);  // smaller col wins ties
            if (key > best) best = key;
        }
        col = 0x1FFF - (int)(best & 0xFFFFu);
    }

    // gather: out[row, :] = WgT[col, :]   (both rows 16B-aligned: 1000*4 = 4000 B)
    const float4* src = (const float4*)(WgT + (size_t)col * NCLS);
    float4* dst = (float4*)(out + (size_t)row * NCLS);
    for (int t = lane; t < NCLS / 4; t += 64) dst[t] = src[t];
}

// ---------- round-1 fp32 fallback (used only if ws too small) ----------
__global__ void init_ws_kernel(u64* rowkey) {
    int i = blockIdx.x * blockDim.x + threadIdx.x;
    if (i < BATCH) rowkey[i] = 0ULL;
}

__global__ __launch_bounds__(256) void gemm_argmax_kernel(
    const float* __restrict__ x, const float* __restrict__ Wk,
    u64* __restrict__ rowkey)
{
    __shared__ __align__(16) float As[32 * 64];
    __shared__ __align__(16) float Bs[32 * 64];
    const int tid = threadIdx.x;
    const int bm = blockIdx.y * 64, bn = blockIdx.x * 64;
    const int tx = tid & 15, ty = tid >> 4;
    float acc[4][4];
    #pragma unroll
    for (int i = 0; i < 4; i++)
        #pragma unroll
        for (int j = 0; j < 4; j++) acc[i][j] = 0.f;
    const int r0 = tid >> 3, q0 = tid & 7;
    const int r1 = (tid + 256) >> 3, q1 = (tid + 256) & 7;
    const float* xA0 = &x[(size_t)(bm + r0) * IN + q0 * 4];
    const float* xA1 = &x[(size_t)(bm + r1) * IN + q1 * 4];
    const float* wB0 = &Wk[(size_t)(bn + r0) * IN + q0 * 4];
    const float* wB1 = &Wk[(size_t)(bn + r1) * IN + q1 * 4];
    for (int k0 = 0; k0 < IN; k0 += 32) {
        float4 a0 = *(const float4*)(xA0 + k0);
        float4 a1 = *(const float4*)(xA1 + k0);
        float4 b0 = *(const float4*)(wB0 + k0);
        float4 b1 = *(const float4*)(wB1 + k0);
        __syncthreads();
        As[(q0 * 4 + 0) * 64 + r0] = a0.x; As[(q0 * 4 + 1) * 64 + r0] = a0.y;
        As[(q0 * 4 + 2) * 64 + r0] = a0.z; As[(q0 * 4 + 3) * 64 + r0] = a0.w;
        As[(q1 * 4 + 0) * 64 + r1] = a1.x; As[(q1 * 4 + 1) * 64 + r1] = a1.y;
        As[(q1 * 4 + 2) * 64 + r1] = a1.z; As[(q1 * 4 + 3) * 64 + r1] = a1.w;
        Bs[(q0 * 4 + 0) * 64 + r0] = b0.x; Bs[(q0 * 4 + 1) * 64 + r0] = b0.y;
        Bs[(q0 * 4 + 2) * 64 + r0] = b0.z; Bs[(q0 * 4 + 3) * 64 + r0] = b0.w;
        Bs[(q1 * 4 + 0) * 64 + r1] = b1.x; Bs[(q1 * 4 + 1) * 64 + r1] = b1.y;
        Bs[(q1 * 4 + 2) * 64 + r1] = b1.z; Bs[(q1 * 4 + 3) * 64 + r1] = b1.w;
        __syncthreads();
        #pragma unroll
        for (int k = 0; k < 32; k++) {
            float4 av = *(const float4*)&As[k * 64 + ty * 4];
            float4 bv = *(const float4*)&Bs[k * 64 + tx * 4];
            acc[0][0] += av.x * bv.x; acc[0][1] += av.x * bv.y;
            acc[0][2] += av.x * bv.z; acc[0][3] += av.x * bv.w;
            acc[1][0] += av.y * bv.x; acc[1][1] += av.y * bv.y;
            acc[1][2] += av.y * bv.z; acc[1][3] += av.y * bv.w;
            acc[2][0] += av.z * bv.x; acc[2][1] += av.z * bv.y;
            acc[2][2] += av.z * bv.z; acc[2][3] += av.z * bv.w;
            acc[3][0] += av.w * bv.x; acc[3][1] += av.w * bv.y;
            acc[3][2] += av.w * bv.z; acc[3][3] += av.w * bv.w;
        }
    }
    #pragma unroll
    for (int i = 0; i < 4; i++) {
        const int row = bm + ty * 4 + i;
        u64 best = 0ULL;
        #pragma unroll
        for (int j = 0; j < 4; j++) {
            const int col = bn + tx * 4 + j;
            u64 p = ((u64)fkey(acc[i][j]) << 32) | (u64)(0x1FFFu - (unsigned)col);
            if (p > best) best = p;
        }
        #pragma unroll
        for (int off = 1; off < 16; off <<= 1) {
            u64 other = __shfl_xor(best, off, 64);
            if (other > best) best = other;
        }
        if (tx == 0) atomicMax(&rowkey[row], best);
    }
}

__global__ __launch_bounds__(256) void gather_kernel(
    const u64* __restrict__ rowkey, const float* __restrict__ Wg,
    float* __restrict__ out)
{
    const int b = blockIdx.y;
    const int c = blockIdx.x * 256 + threadIdx.x;
    if (c >= NCLS) return;
    const int col = 0x1FFF - (int)(rowkey[b] & 0xFFFFFFFFu);
    out[(size_t)b * NCLS + c] = Wg[(size_t)c * HID + col];
}

// ---------- launch ----------
extern "C" void kernel_launch(void* const* d_in, const int* in_sizes, int n_in,
                              void* d_out, int out_size, void* d_ws, size_t ws_size,
                              hipStream_t stream) {
    const float* x  = (const float*)d_in[0];
    const float* Wk = (const float*)d_in[1];
    const float* Wg = (const float*)d_in[2];
    float* out = (float*)d_out;
    char* ws = (char*)d_ws;

    if (ws_size >= TOTAL_FULL) {
        u32* topk  = (u32*)(ws + OFF_TOPK);
        u8*  x8    = (u8*)(ws + OFF_X8);
        u8*  wk8   = (u8*)(ws + OFF_WK8);
        float* WgT = (float*)(ws + OFF_WGT);

        hipLaunchKernelGGL(prep_kernel, dim3(1024 + 8192), dim3(256), 0, stream,
                           x, Wk, Wg, x8, wk8, WgT);
        hipLaunchKernelGGL(mfma_fp8_gemm_kernel, dim3(HID / 256, BATCH / 128), dim3(512), 0, stream,
                           x8, wk8, topk);
        hipLaunchKernelGGL(scan_kernel, dim3(BATCH / 4), dim3(256), 0, stream,
                           topk, x, Wk, WgT, out);
    } else {
        u64* rowkey = (u64*)(ws + OFF_ROWKEY);
        hipLaunchKernelGGL(init_ws_kernel, dim3(16), dim3(256), 0, stream, rowkey);
        hipLaunchKernelGGL(gemm_argmax_kernel, dim3(HID / 64, BATCH / 64), dim3(256), 0, stream,
                           x, Wk, rowkey);
        hipLaunchKernelGGL(gather_kernel, dim3(4, BATCH), dim3(256), 0, stream,
                           rowkey, Wg, out);
    }
}

// Round 4
// 318.150 us; speedup vs baseline: 2.2109x; 2.2109x over previous
//
#include <hip/hip_runtime.h>
#include <stdint.h>

typedef unsigned int u32;
typedef unsigned long long u64;
typedef unsigned short u16;
typedef unsigned char u8;
typedef int intx8 __attribute__((ext_vector_type(8)));
typedef float floatx4 __attribute__((ext_vector_type(4)));

#define BATCH 4096
#define IN    2048
#define HID   8192
#define NCLS  1000

// ---------- ws layout (bytes) ----------
#define OFF_ROWKEY 0u                       // u64[4096]      32 KB (fallback)
#define OFF_TOPK   32768u                   // u32[4096*512]   8 MB
#define OFF_X8     8421376u                 // fp8 x           8 MB
#define OFF_WK8    16809984u                // fp8 Wk         16 MB
#define OFF_WGT    33587200u                // fp32 Wg^T   31.25 MB
#define TOTAL_FULL 66355200ull

// ---------- helpers ----------
__device__ __forceinline__ u32 fkey(float f) {          // monotonic float->u32
    u32 u = __float_as_uint(f);
    return (u & 0x80000000u) ? ~u : (u | 0x80000000u);
}
__device__ __forceinline__ float unfkey(u32 k) {
    return __uint_as_float((k & 0x80000000u) ? (k ^ 0x80000000u) : ~k);
}
__device__ __forceinline__ void ce32(u32& a, u32& b) {  // desc compare-exchange (2 ops)
    u32 mx = a > b ? a : b;
    u32 mn = a > b ? b : a;
    a = mx; b = mn;
}

// ---------- prep: convert x & Wk to fp8 e4m3 (unit scale), transpose Wg ----------
__global__ __launch_bounds__(256) void prep_kernel(
    const float* __restrict__ x, const float* __restrict__ Wk,
    const float* __restrict__ Wg,
    u8* __restrict__ x8, u8* __restrict__ wk8, float* __restrict__ WgT)
{
    __shared__ float t[32][33];
    const int bid = blockIdx.x;
    if (bid < 1024) {
        const int gid = bid * 256 + threadIdx.x;
        const int NSX = BATCH * IN / 16;          // 524288
        const int NS  = NSX + HID * IN / 16;      // 1572864
        for (int s = gid; s < NS; s += 1024 * 256) {
            const float4* src; u8* dst;
            if (s < NSX) { src = (const float4*)x + (size_t)s * 4;  dst = x8  + (size_t)s * 16; }
            else { int u = s - NSX; src = (const float4*)Wk + (size_t)u * 4; dst = wk8 + (size_t)u * 16; }
            uint4 o;
            float4 f;
            int p;
            f = src[0];
            p = __builtin_amdgcn_cvt_pk_fp8_f32(f.x, f.y, 0, false);
            p = __builtin_amdgcn_cvt_pk_fp8_f32(f.z, f.w, p, true);  o.x = (u32)p;
            f = src[1];
            p = __builtin_amdgcn_cvt_pk_fp8_f32(f.x, f.y, 0, false);
            p = __builtin_amdgcn_cvt_pk_fp8_f32(f.z, f.w, p, true);  o.y = (u32)p;
            f = src[2];
            p = __builtin_amdgcn_cvt_pk_fp8_f32(f.x, f.y, 0, false);
            p = __builtin_amdgcn_cvt_pk_fp8_f32(f.z, f.w, p, true);  o.z = (u32)p;
            f = src[3];
            p = __builtin_amdgcn_cvt_pk_fp8_f32(f.x, f.y, 0, false);
            p = __builtin_amdgcn_cvt_pk_fp8_f32(f.z, f.w, p, true);  o.w = (u32)p;
            *(uint4*)dst = o;
        }
    } else {
        const int tb = bid - 1024;
        const int bx = (tb & 255) * 32;   // HID
        const int by = (tb >> 8) * 32;    // NCLS
        const int tx = threadIdx.x & 31, ty = threadIdx.x >> 5;  // ty 0..7
        #pragma unroll
        for (int i = 0; i < 32; i += 8) {
            int c = by + ty + i;
            t[ty + i][tx] = (c < NCLS) ? Wg[(size_t)c * HID + bx + tx] : 0.f;
        }
        __syncthreads();
        #pragma unroll
        for (int i = 0; i < 32; i += 8) {
            int c = by + tx;
            if (c < NCLS) WgT[(size_t)(bx + ty + i) * NCLS + by + tx] = t[tx][ty + i];
        }
    }
}

// ---------- fp8 MFMA GEMM: 256x256 block, 8 waves of 128x64, dbuf, 4 phases ----------
// ROUND-4 FIX: round 3 dropped "+ ldst" from every STG LDS destination -> all
// 8 waves wrote the same first KB of each region, rows 8..63 stale -> absmax 2.
// Structure otherwise audited sound; restored ldst everywhere.
// Geometry theory (round 3): LDS fragment traffic per wave per K-tile =
// (Wm+Wn)*128B. 64x64 wave tiles (rounds 0-2) -> LDS:MFMA ratio 1.4
// (LDS-bound); 128x64 wave tiles -> 0.87 (MFMA-bound). Math bit-identical to
// round 0: same fp8 data, granule-XOR swizzle, MFMA order, top-4 epilogue.
//   - LDS: 2 buffers x (A 32KB + B 32KB) = 128 KB; row r at r*128 (A),
//     32768+r*128 (B). Stage unit = 64 rows = 8KB = one STG x 512 threads.
//   - per K-tile, 4 phases: {ds_read subtile; 2 stage units(kt+1); barrier;
//     lgkmcnt(0); setprio(1); 8 MFMA; setprio(0); [vmcnt(N)]; barrier}
//   - stage order per tile: A0,A2 | B0,B1 | B2,B3 | A1,A3. Invariant: at kt
//     entry exactly {A1,A3(kt)} outstanding. vmcnt(4) at P1-end drains them
//     (P2 needs those rows); vmcnt(2) at P3-end drains kt+1's first six
//     (its P0/P1 needs). Never vmcnt(0) in steady state.
// Register budget: acc 128 + af 32 + bf 32 + addr ~25 = ~220 < 256
// (__launch_bounds__(512,2)). Spill guard: WRITE_SIZE must stay ~8 MB.
#define STG(gsrc, ldsoff) \
    __builtin_amdgcn_global_load_lds((const __attribute__((address_space(1))) u32*)(gsrc), \
        (__attribute__((address_space(3))) u32*)&LDS[ldsoff], 16, 0, 0)

#define MFMA1(A_, B_, C_) C_ = __builtin_amdgcn_mfma_scale_f32_16x16x128_f8f6f4( \
    A_, B_, C_, 0, 0, 0, 0x7F, 0, 0x7F)

__global__ __launch_bounds__(512, 2) void mfma_fp8_gemm_kernel(
    const u8* __restrict__ x8, const u8* __restrict__ wk8,
    u32* __restrict__ topk)
{
    __shared__ __align__(16) u8 LDS[2 * 65536];   // 128 KB

    const int tid  = threadIdx.x;
    const int lane = tid & 63;
    const int w    = tid >> 6;                    // 0..7
    const int bm   = blockIdx.y * 256;
    const int bn   = blockIdx.x * 256;
    const int wrow = (w >> 2) * 128;              // 0 or 128
    const int wcol = (w & 3) * 64;                // 0,64,128,192
    const int m = lane & 15, q = lane >> 4;

    floatx4 acc[8][4];
    #pragma unroll
    for (int i = 0; i < 8; i++)
        #pragma unroll
        for (int j = 0; j < 4; j++)
            acc[i][j] = (floatx4){0.f, 0.f, 0.f, 0.f};

    // staging: 512 threads cover one 64-row unit (8 KB) per STG; source 16B
    // chunk permuted so physical granule p of row r holds logical p^(r&3)
    const int srow = tid >> 3;                                        // 0..63
    const int soff = (((((tid >> 1) & 3) ^ (srow & 3)) * 2) + (tid & 1)) * 16;
    const u8* gxa = x8  + (size_t)(bm + srow) * IN + soff;
    const u8* gwb = wk8 + (size_t)(bn + srow) * IN + soff;
    const u32 ldst = (u32)tid * 16;

    // fragment read: logical granule q of row r sits at physical q^(r&3)
    const u32 foq = (u32)((q ^ (m & 3)) * 32);

    // ---- prologue: stage kt0 -> buf0, order A0,A2,B0,B1,B2,B3,A1,A3 ----
    STG(gxa,                      0u     + ldst);
    STG(gxa + 128 * (size_t)IN,   16384u + ldst);
    STG(gwb,                      32768u + ldst);
    STG(gwb +  64 * (size_t)IN,   40960u + ldst);
    STG(gwb + 128 * (size_t)IN,   49152u + ldst);
    STG(gwb + 192 * (size_t)IN,   57344u + ldst);
    STG(gxa +  64 * (size_t)IN,   8192u  + ldst);
    STG(gxa + 192 * (size_t)IN,   24576u + ldst);
    asm volatile("s_waitcnt vmcnt(2)" ::: "memory");   // first 6 landed
    __builtin_amdgcn_s_barrier();

    u32 cb = 0u;   // current buffer base

    intx8 af[4], bf[4];

    #pragma unroll 1
    for (int kt = 0; kt < 16; ++kt) {
        const u32 nb = cb ^ 65536u;
        const size_t ko = (size_t)(kt + 1) * 128;
        // ---------------- P0: read A i0-3, B j0-1; stage A0,A2 ----------------
        #pragma unroll
        for (int i = 0; i < 4; i++)
            af[i] = *(const intx8*)&LDS[cb + (u32)(wrow + i * 16 + m) * 128u + foq];
        #pragma unroll
        for (int j = 0; j < 2; j++)
            bf[j] = *(const intx8*)&LDS[cb + 32768u + (u32)(wcol + j * 16 + m) * 128u + foq];
        if (kt < 15) {
            STG(gxa + ko,                     nb + ldst);
            STG(gxa + 128 * (size_t)IN + ko,  nb + 16384u + ldst);
        }
        asm volatile("" ::: "memory");
        __builtin_amdgcn_s_barrier();
        asm volatile("s_waitcnt lgkmcnt(0)" ::: "memory");
        __builtin_amdgcn_sched_barrier(0);
        __builtin_amdgcn_s_setprio(1);
        #pragma unroll
        for (int i = 0; i < 4; i++) { MFMA1(af[i], bf[0], acc[i][0]); }
        #pragma unroll
        for (int i = 0; i < 4; i++) { MFMA1(af[i], bf[1], acc[i][1]); }
        __builtin_amdgcn_s_setprio(0);
        asm volatile("" ::: "memory");
        __builtin_amdgcn_s_barrier();
        // ---------------- P1: read B j2-3; stage B0,B1 ----------------
        #pragma unroll
        for (int j = 2; j < 4; j++)
            bf[j] = *(const intx8*)&LDS[cb + 32768u + (u32)(wcol + j * 16 + m) * 128u + foq];
        if (kt < 15) {
            STG(gwb + ko,                     nb + 32768u + ldst);
            STG(gwb +  64 * (size_t)IN + ko,  nb + 40960u + ldst);
        }
        asm volatile("" ::: "memory");
        __builtin_amdgcn_s_barrier();
        asm volatile("s_waitcnt lgkmcnt(0)" ::: "memory");
        __builtin_amdgcn_sched_barrier(0);
        __builtin_amdgcn_s_setprio(1);
        #pragma unroll
        for (int i = 0; i < 4; i++) { MFMA1(af[i], bf[2], acc[i][2]); }
        #pragma unroll
        for (int i = 0; i < 4; i++) { MFMA1(af[i], bf[3], acc[i][3]); }
        __builtin_amdgcn_s_setprio(0);
        // drain this tile's A1,A3 (needed by P2); keep kt+1's 4 stages flying
        if (kt < 15) asm volatile("s_waitcnt vmcnt(4)" ::: "memory");
        else         asm volatile("s_waitcnt vmcnt(0)" ::: "memory");
        __builtin_amdgcn_s_barrier();
        // ---------------- P2: read A i4-7; stage B2,B3 ----------------
        #pragma unroll
        for (int i = 0; i < 4; i++)
            af[i] = *(const intx8*)&LDS[cb + (u32)(wrow + 64 + i * 16 + m) * 128u + foq];
        if (kt < 15) {
            STG(gwb + 128 * (size_t)IN + ko,  nb + 49152u + ldst);
            STG(gwb + 192 * (size_t)IN + ko,  nb + 57344u + ldst);
        }
        asm volatile("" ::: "memory");
        __builtin_amdgcn_s_barrier();
        asm volatile("s_waitcnt lgkmcnt(0)" ::: "memory");
        __builtin_amdgcn_sched_barrier(0);
        __builtin_amdgcn_s_setprio(1);
        #pragma unroll
        for (int i = 0; i < 4; i++) { MFMA1(af[i], bf[0], acc[4 + i][0]); }
        #pragma unroll
        for (int i = 0; i < 4; i++) { MFMA1(af[i], bf[1], acc[4 + i][1]); }
        __builtin_amdgcn_s_setprio(0);
        asm volatile("" ::: "memory");
        __builtin_amdgcn_s_barrier();
        // ---------------- P3: stage A1,A3 ----------------
        if (kt < 15) {
            STG(gxa +  64 * (size_t)IN + ko,  nb + 8192u  + ldst);
            STG(gxa + 192 * (size_t)IN + ko,  nb + 24576u + ldst);
        }
        asm volatile("" ::: "memory");
        __builtin_amdgcn_s_barrier();
        __builtin_amdgcn_s_setprio(1);
        #pragma unroll
        for (int i = 0; i < 4; i++) { MFMA1(af[i], bf[2], acc[4 + i][2]); }
        #pragma unroll
        for (int i = 0; i < 4; i++) { MFMA1(af[i], bf[3], acc[4 + i][3]); }
        __builtin_amdgcn_s_setprio(0);
        // drain next tile's first-6 (needed at its P0); keep A1,A3 flying
        if (kt < 15) asm volatile("s_waitcnt vmcnt(2)" ::: "memory");
        __builtin_amdgcn_s_barrier();
        cb = nb;
    }

    // epilogue: per-row top-4 (u32 keys) over this wave's 64 columns
    const int group = blockIdx.x * 4 + (w & 3);   // 64-col group id, 0..127
    #pragma unroll
    for (int i = 0; i < 8; i++) {
        #pragma unroll
        for (int r = 0; r < 4; r++) {
            u32 k0 = (fkey(acc[i][0][r]) & 0xFFFFFFC0u) | (0u << 4) | (u32)m;
            u32 k1 = (fkey(acc[i][1][r]) & 0xFFFFFFC0u) | (1u << 4) | (u32)m;
            u32 k2 = (fkey(acc[i][2][r]) & 0xFFFFFFC0u) | (2u << 4) | (u32)m;
            u32 k3 = (fkey(acc[i][3][r]) & 0xFFFFFFC0u) | (3u << 4) | (u32)m;
            // sort 4 desc
            ce32(k0, k1); ce32(k2, k3); ce32(k0, k2); ce32(k1, k3); ce32(k1, k2);
            // butterfly top-4 merge over the 16 lanes sharing this row
            #pragma unroll
            for (int off = 1; off < 16; off <<= 1) {
                u32 b0 = __shfl_xor(k0, off, 64);
                u32 b1 = __shfl_xor(k1, off, 64);
                u32 b2 = __shfl_xor(k2, off, 64);
                u32 b3 = __shfl_xor(k3, off, 64);
                u32 t0 = k0 > b3 ? k0 : b3;    // bitonic keep-max
                u32 t1 = k1 > b2 ? k1 : b2;
                u32 t2 = k2 > b1 ? k2 : b1;
                u32 t3 = k3 > b0 ? k3 : b0;
                ce32(t0, t2); ce32(t1, t3); ce32(t0, t1); ce32(t2, t3);
                k0 = t0; k1 = t1; k2 = t2; k3 = t3;
            }
            if (m == 0) {
                const int grow = bm + wrow + i * 16 + q * 4 + r;
                uint4 v; v.x = k0; v.y = k1; v.z = k2; v.w = k3;
                *(uint4*)&topk[(size_t)grow * 512 + group * 4] = v;
            }
        }
    }
}

// ---------- scan: one WAVE per row; ballot compaction; exact rescore; gather ----------
__global__ __launch_bounds__(256) void scan_kernel(
    const u32* __restrict__ topk,
    const float* __restrict__ x, const float* __restrict__ Wk,
    const float* __restrict__ WgT, float* __restrict__ out)
{
    __shared__ u16 cand[4][48];
    const int wv   = threadIdx.x >> 6;
    const int lane = threadIdx.x & 63;
    const int row  = blockIdx.x * 4 + wv;

    const uint4* tp = (const uint4*)(topk + (size_t)row * 512);
    uint4 v0 = tp[lane];        // group = lane
    uint4 v1 = tp[lane + 64];   // group = lane + 64

    // row max (u32 keys are value-ordered; id bits only break near-ties)
    u32 mx = v0.x > v1.x ? v0.x : v1.x;   // slot 0 of each uint4 is its group's max
    #pragma unroll
    for (int off = 1; off < 64; off <<= 1) {
        u32 o = __shfl_xor(mx, off, 64);
        if (o > mx) mx = o;
    }
    const float thr = unfkey(mx & 0xFFFFFFC0u) - 12.0f;

    // ballot-compact in-window candidates into per-wave LDS (no atomics)
    int base = 0;
    const u32 ks[8] = {v0.x, v0.y, v0.z, v0.w, v1.x, v1.y, v1.z, v1.w};
    #pragma unroll
    for (int s = 0; s < 8; s++) {
        const int group = (s < 4) ? lane : (lane + 64);
        const u32 key = ks[s];
        const bool in = unfkey(key & 0xFFFFFFC0u) >= thr;
        const u64 msk = __ballot(in);
        if (in) {
            int rnk = base + __popcll(msk & ((1ull << lane) - 1ull));
            if (rnk < 48)
                cand[wv][rnk] = (u16)(group * 64 + (int)((key >> 4) & 3u) * 16 + (int)(key & 15u));
        }
        base += __popcll(msk);
    }
    const int n = min(base, 48);
    __builtin_amdgcn_wave_barrier();   // keep compiler from sinking LDS reads above writes

    int col;
    if (n <= 1) {
        col = cand[wv][0];   // the max itself is always in-window
    } else {
        // exact fp32 rescore, whole wave per candidate
        const float4* xr = (const float4*)(x + (size_t)row * IN);
        float4 a[8];
        #pragma unroll
        for (int p = 0; p < 8; p++) a[p] = xr[p * 64 + lane];
        u64 best = 0ull;
        for (int c = 0; c < n; c++) {
            const int h = cand[wv][c];
            const float4* wr = (const float4*)(Wk + (size_t)h * IN);
            float s = 0.f;
            #pragma unroll
            for (int p = 0; p < 8; p++) {
                float4 b = wr[p * 64 + lane];
                s += a[p].x * b.x + a[p].y * b.y + a[p].z * b.z + a[p].w * b.w;
            }
            #pragma unroll
            for (int off = 1; off < 64; off <<= 1) s += __shfl_xor(s, off, 64);
            // s identical on all lanes; track best on all lanes (no broadcast needed)
            u64 key = ((u64)fkey(s) << 32) | (u64)(0x1FFFu - (u32)h);  // smaller col wins ties
            if (key > best) best = key;
        }
        col = 0x1FFF - (int)(best & 0xFFFFu);
    }

    // gather: out[row, :] = WgT[col, :]   (both rows 16B-aligned: 1000*4 = 4000 B)
    const float4* src = (const float4*)(WgT + (size_t)col * NCLS);
    float4* dst = (float4*)(out + (size_t)row * NCLS);
    for (int t = lane; t < NCLS / 4; t += 64) dst[t] = src[t];
}

// ---------- round-1 fp32 fallback (used only if ws too small) ----------
__global__ void init_ws_kernel(u64* rowkey) {
    int i = blockIdx.x * blockDim.x + threadIdx.x;
    if (i < BATCH) rowkey[i] = 0ULL;
}

__global__ __launch_bounds__(256) void gemm_argmax_kernel(
    const float* __restrict__ x, const float* __restrict__ Wk,
    u64* __restrict__ rowkey)
{
    __shared__ __align__(16) float As[32 * 64];
    __shared__ __align__(16) float Bs[32 * 64];
    const int tid = threadIdx.x;
    const int bm = blockIdx.y * 64, bn = blockIdx.x * 64;
    const int tx = tid & 15, ty = tid >> 4;
    float acc[4][4];
    #pragma unroll
    for (int i = 0; i < 4; i++)
        #pragma unroll
        for (int j = 0; j < 4; j++) acc[i][j] = 0.f;
    const int r0 = tid >> 3, q0 = tid & 7;
    const int r1 = (tid + 256) >> 3, q1 = (tid + 256) & 7;
    const float* xA0 = &x[(size_t)(bm + r0) * IN + q0 * 4];
    const float* xA1 = &x[(size_t)(bm + r1) * IN + q1 * 4];
    const float* wB0 = &Wk[(size_t)(bn + r0) * IN + q0 * 4];
    const float* wB1 = &Wk[(size_t)(bn + r1) * IN + q1 * 4];
    for (int k0 = 0; k0 < IN; k0 += 32) {
        float4 a0 = *(const float4*)(xA0 + k0);
        float4 a1 = *(const float4*)(xA1 + k0);
        float4 b0 = *(const float4*)(wB0 + k0);
        float4 b1 = *(const float4*)(wB1 + k0);
        __syncthreads();
        As[(q0 * 4 + 0) * 64 + r0] = a0.x; As[(q0 * 4 + 1) * 64 + r0] = a0.y;
        As[(q0 * 4 + 2) * 64 + r0] = a0.z; As[(q0 * 4 + 3) * 64 + r0] = a0.w;
        As[(q1 * 4 + 0) * 64 + r1] = a1.x; As[(q1 * 4 + 1) * 64 + r1] = a1.y;
        As[(q1 * 4 + 2) * 64 + r1] = a1.z; As[(q1 * 4 + 3) * 64 + r1] = a1.w;
        Bs[(q0 * 4 + 0) * 64 + r0] = b0.x; Bs[(q0 * 4 + 1) * 64 + r0] = b0.y;
        Bs[(q0 * 4 + 2) * 64 + r0] = b0.z; Bs[(q0 * 4 + 3) * 64 + r0] = b0.w;
        Bs[(q1 * 4 + 0) * 64 + r1] = b1.x; Bs[(q1 * 4 + 1) * 64 + r1] = b1.y;
        Bs[(q1 * 4 + 2) * 64 + r1] = b1.z; Bs[(q1 * 4 + 3) * 64 + r1] = b1.w;
        __syncthreads();
        #pragma unroll
        for (int k = 0; k < 32; k++) {
            float4 av = *(const float4*)&As[k * 64 + ty * 4];
            float4 bv = *(const float4*)&Bs[k * 64 + tx * 4];
            acc[0][0] += av.x * bv.x; acc[0][1] += av.x * bv.y;
            acc[0][2] += av.x * bv.z; acc[0][3] += av.x * bv.w;
            acc[1][0] += av.y * bv.x; acc[1][1] += av.y * bv.y;
            acc[1][2] += av.y * bv.z; acc[1][3] += av.y * bv.w;
            acc[2][0] += av.z * bv.x; acc[2][1] += av.z * bv.y;
            acc[2][2] += av.z * bv.z; acc[2][3] += av.z * bv.w;
            acc[3][0] += av.w * bv.x; acc[3][1] += av.w * bv.y;
            acc[3][2] += av.w * bv.z; acc[3][3] += av.w * bv.w;
        }
    }
    #pragma unroll
    for (int i = 0; i < 4; i++) {
        const int row = bm + ty * 4 + i;
        u64 best = 0ULL;
        #pragma unroll
        for (int j = 0; j < 4; j++) {
            const int col = bn + tx * 4 + j;
            u64 p = ((u64)fkey(acc[i][j]) << 32) | (u64)(0x1FFFu - (unsigned)col);
            if (p > best) best = p;
        }
        #pragma unroll
        for (int off = 1; off < 16; off <<= 1) {
            u64 other = __shfl_xor(best, off, 64);
            if (other > best) best = other;
        }
        if (tx == 0) atomicMax(&rowkey[row], best);
    }
}

__global__ __launch_bounds__(256) void gather_kernel(
    const u64* __restrict__ rowkey, const float* __restrict__ Wg,
    float* __restrict__ out)
{
    const int b = blockIdx.y;
    const int c = blockIdx.x * 256 + threadIdx.x;
    if (c >= NCLS) return;
    const int col = 0x1FFF - (int)(rowkey[b] & 0xFFFFFFFFu);
    out[(size_t)b * NCLS + c] = Wg[(size_t)c * HID + col];
}

// ---------- launch ----------
extern "C" void kernel_launch(void* const* d_in, const int* in_sizes, int n_in,
                              void* d_out, int out_size, void* d_ws, size_t ws_size,
                              hipStream_t stream) {
    const float* x  = (const float*)d_in[0];
    const float* Wk = (const float*)d_in[1];
    const float* Wg = (const float*)d_in[2];
    float* out = (float*)d_out;
    char* ws = (char*)d_ws;

    if (ws_size >= TOTAL_FULL) {
        u32* topk  = (u32*)(ws + OFF_TOPK);
        u8*  x8    = (u8*)(ws + OFF_X8);
        u8*  wk8   = (u8*)(ws + OFF_WK8);
        float* WgT = (float*)(ws + OFF_WGT);

        hipLaunchKernelGGL(prep_kernel, dim3(1024 + 8192), dim3(256), 0, stream,
                           x, Wk, Wg, x8, wk8, WgT);
        hipLaunchKernelGGL(mfma_fp8_gemm_kernel, dim3(HID / 256, BATCH / 256), dim3(512), 0, stream,
                           x8, wk8, topk);
        hipLaunchKernelGGL(scan_kernel, dim3(BATCH / 4), dim3(256), 0, stream,
                           topk, x, Wk, WgT, out);
    } else {
        u64* rowkey = (u64*)(ws + OFF_ROWKEY);
        hipLaunchKernelGGL(init_ws_kernel, dim3(16), dim3(256), 0, stream, rowkey);
        hipLaunchKernelGGL(gemm_argmax_kernel, dim3(HID / 64, BATCH / 64), dim3(256), 0, stream,
                           x, Wk, rowkey);
        hipLaunchKernelGGL(gather_kernel, dim3(4, BATCH), dim3(256), 0, stream,
                           rowkey, Wg, out);
    }
}

// Round 5
// 306.641 us; speedup vs baseline: 2.2939x; 1.0375x over previous
//
#include <hip/hip_runtime.h>
#include <stdint.h>

typedef unsigned int u32;
typedef unsigned long long u64;
typedef unsigned short u16;
typedef unsigned char u8;
typedef int intx4 __attribute__((ext_vector_type(4)));
typedef int intx8 __attribute__((ext_vector_type(8)));
typedef float floatx4 __attribute__((ext_vector_type(4)));

#define BATCH 4096
#define IN    2048
#define HID   8192
#define NCLS  1000

// ---------- ws layout (bytes) ----------
#define OFF_ROWKEY 0u                       // u64[4096]      32 KB (fallback)
#define OFF_TOPK   32768u                   // u32[4096*512]   8 MB
#define OFF_X8     8421376u                 // fp8 x           8 MB
#define OFF_WK8    16809984u                // fp8 Wk         16 MB
#define OFF_WGT    33587200u                // fp32 Wg^T   31.25 MB
#define TOTAL_FULL 66355200ull

// ---------- helpers ----------
__device__ __forceinline__ u32 fkey(float f) {          // monotonic float->u32
    u32 u = __float_as_uint(f);
    return (u & 0x80000000u) ? ~u : (u | 0x80000000u);
}
__device__ __forceinline__ float unfkey(u32 k) {
    return __uint_as_float((k & 0x80000000u) ? (k ^ 0x80000000u) : ~k);
}
__device__ __forceinline__ void ce32(u32& a, u32& b) {  // desc compare-exchange (2 ops)
    u32 mx = a > b ? a : b;
    u32 mn = a > b ? b : a;
    a = mx; b = mn;
}

// ---------- prep: convert x & Wk to fp8 e4m3 (unit scale), transpose Wg ----------
__global__ __launch_bounds__(256) void prep_kernel(
    const float* __restrict__ x, const float* __restrict__ Wk,
    const float* __restrict__ Wg,
    u8* __restrict__ x8, u8* __restrict__ wk8, float* __restrict__ WgT)
{
    __shared__ float t[32][33];
    const int bid = blockIdx.x;
    if (bid < 1024) {
        const int gid = bid * 256 + threadIdx.x;
        const int NSX = BATCH * IN / 16;          // 524288
        const int NS  = NSX + HID * IN / 16;      // 1572864
        for (int s = gid; s < NS; s += 1024 * 256) {
            const float4* src; u8* dst;
            if (s < NSX) { src = (const float4*)x + (size_t)s * 4;  dst = x8  + (size_t)s * 16; }
            else { int u = s - NSX; src = (const float4*)Wk + (size_t)u * 4; dst = wk8 + (size_t)u * 16; }
            uint4 o;
            float4 f;
            int p;
            f = src[0];
            p = __builtin_amdgcn_cvt_pk_fp8_f32(f.x, f.y, 0, false);
            p = __builtin_amdgcn_cvt_pk_fp8_f32(f.z, f.w, p, true);  o.x = (u32)p;
            f = src[1];
            p = __builtin_amdgcn_cvt_pk_fp8_f32(f.x, f.y, 0, false);
            p = __builtin_amdgcn_cvt_pk_fp8_f32(f.z, f.w, p, true);  o.y = (u32)p;
            f = src[2];
            p = __builtin_amdgcn_cvt_pk_fp8_f32(f.x, f.y, 0, false);
            p = __builtin_amdgcn_cvt_pk_fp8_f32(f.z, f.w, p, true);  o.z = (u32)p;
            f = src[3];
            p = __builtin_amdgcn_cvt_pk_fp8_f32(f.x, f.y, 0, false);
            p = __builtin_amdgcn_cvt_pk_fp8_f32(f.z, f.w, p, true);  o.w = (u32)p;
            *(uint4*)dst = o;
        }
    } else {
        const int tb = bid - 1024;
        const int bx = (tb & 255) * 32;   // HID
        const int by = (tb >> 8) * 32;    // NCLS
        const int tx = threadIdx.x & 31, ty = threadIdx.x >> 5;  // ty 0..7
        #pragma unroll
        for (int i = 0; i < 32; i += 8) {
            int c = by + ty + i;
            t[ty + i][tx] = (c < NCLS) ? Wg[(size_t)c * HID + bx + tx] : 0.f;
        }
        __syncthreads();
        #pragma unroll
        for (int i = 0; i < 32; i += 8) {
            int c = by + tx;
            if (c < NCLS) WgT[(size_t)(bx + ty + i) * NCLS + by + tx] = t[tx][ty + i];
        }
    }
}

// ---------- fp8 MFMA GEMM: 256x256, 8 waves of 128x64, 1 barrier/K-tile ----------
// Round-5 diagnosis: rounds 0/1/4 all ~25% MfmaUtil across 3 schedules. Shared
// flaws: (1) fragments are 32B/lane (2x b128) -> LDS 192KB/CU/K-tile ~= MFMA
// time, so any serialization is fatal; (2) granule-XOR swizzle = inherent
// 4-way bank conflict (4 lanes per 32B granule in each 16-lane row group);
// (3) 8 barriers/K-tile. Fixes:
//   - 8-slot 16B XOR swizzle (round-1's, proven correct): physical chunk
//     p = c ^ (row&7); fragment = b128 pair at addr, addr^16; every 8-lane
//     subgroup covers all 8 chunks -> 2 lanes/bank = conflict-free (m136).
//     Staging source-permutes within each 128B row (coalescing kept).
//   - ONE barrier per K-tile (clean whole-tile dbuf): each wave does
//     lgkmcnt(0) [its reads of buf[kt] done] + vmcnt(0) [its stages of
//     buf[kt+1] landed, issued ~2400cy earlier] before the barrier; after it,
//     buf[kt+1] is proven staged and buf[kt] is free to overwrite. All other
//     barriers were redundant: stages never touch the buffer being read.
//   - 32 MFMA between syncs (two 16-clusters); afH reads REUSE af regs
//     (sched_barrier(0) fence prevents hoisting into fresh regs -> r2 spill).
// Math bit-identical: same fp8 data, same fragment contents (logical chunks
// 2q,2q+1 of row), same MFMA per accumulator, same epilogue.
// Register budget: af 32 + bf 32 + addrs ~25 arch + acc 128 (AGPR) < 256.
// Spill guard: WRITE_SIZE must stay ~8.2 MB.
#define STG(gsrc, ldsoff) \
    __builtin_amdgcn_global_load_lds((const __attribute__((address_space(1))) u32*)(gsrc), \
        (__attribute__((address_space(3))) u32*)&LDS[ldsoff], 16, 0, 0)

#define RD8(dst, off) { \
    intx4 lo_ = *(const intx4*)&LDS[(off)]; \
    intx4 hi_ = *(const intx4*)&LDS[(off) ^ 16u]; \
    dst = __builtin_shufflevector(lo_, hi_, 0, 1, 2, 3, 4, 5, 6, 7); }

#define MFMA1(A_, B_, C_) C_ = __builtin_amdgcn_mfma_scale_f32_16x16x128_f8f6f4( \
    A_, B_, C_, 0, 0, 0, 0x7F, 0, 0x7F)

__global__ __launch_bounds__(512, 2) void mfma_fp8_gemm_kernel(
    const u8* __restrict__ x8, const u8* __restrict__ wk8,
    u32* __restrict__ topk)
{
    __shared__ __align__(16) u8 LDS[2 * 65536];   // 128 KB

    const int tid  = threadIdx.x;
    const int lane = tid & 63;
    const int w    = tid >> 6;                    // 0..7
    const int bm   = blockIdx.y * 256;
    const int bn   = blockIdx.x * 256;
    const int wrow = (w >> 2) * 128;              // 0 or 128
    const int wcol = (w & 3) * 64;                // 0,64,128,192
    const int m = lane & 15, q = lane >> 4;

    floatx4 acc[8][4];
    #pragma unroll
    for (int i = 0; i < 8; i++)
        #pragma unroll
        for (int j = 0; j < 4; j++)
            acc[i][j] = (floatx4){0.f, 0.f, 0.f, 0.f};

    // staging: 512 threads cover one 64-row unit (8 KB) per STG; physical 16B
    // chunk p = tid&7 of row srow holds logical chunk p ^ (srow&7)
    const int srow = tid >> 3;                                        // 0..63
    const int soff = ((tid & 7) ^ (srow & 7)) * 16;
    const u8* gxa = x8  + (size_t)(bm + srow) * IN + soff;
    const u8* gwb = wk8 + (size_t)(bn + srow) * IN + soff;
    const u32 ldst = (u32)tid * 16;

    // fragment read: logical chunk c of row r sits at physical c^(r&7);
    // row = (wrow|wcol) + i*16 + m, and wrow/wcol/i*16 are multiples of 8,
    // so r&7 = m&7. Lane reads logical chunks 2q, 2q+1 (32B at k=q*32).
    const u32 csel = (u32)((((2 * q) ^ (m & 7))) * 16);
    const u32 rdA  = (u32)(wrow + m) * 128u + csel;             // A at +0
    const u32 rdB  = 32768u + (u32)(wcol + m) * 128u + csel;    // B at +32K

    // ---- prologue: stage buf0 fully ----
    STG(gxa,                      0u     + ldst);
    STG(gxa +  64 * (size_t)IN,   8192u  + ldst);
    STG(gxa + 128 * (size_t)IN,   16384u + ldst);
    STG(gxa + 192 * (size_t)IN,   24576u + ldst);
    STG(gwb,                      32768u + ldst);
    STG(gwb +  64 * (size_t)IN,   40960u + ldst);
    STG(gwb + 128 * (size_t)IN,   49152u + ldst);
    STG(gwb + 192 * (size_t)IN,   57344u + ldst);
    asm volatile("s_waitcnt vmcnt(0)" ::: "memory");
    __builtin_amdgcn_s_barrier();

    u32 cb = 0u;
    intx8 af[4], bf[4];

    #pragma unroll 1
    for (int kt = 0; kt < 16; ++kt) {
        const u32 nb = cb ^ 65536u;
        const size_t ko = (size_t)(kt + 1) * 128;
        // reads for cluster 1: A rows wrow..wrow+63, B all
        RD8(af[0], cb + rdA);
        RD8(af[1], cb + rdA + 2048u);
        RD8(af[2], cb + rdA + 4096u);
        RD8(af[3], cb + rdA + 6144u);
        RD8(bf[0], cb + rdB);
        RD8(bf[1], cb + rdB + 2048u);
        RD8(bf[2], cb + rdB + 4096u);
        RD8(bf[3], cb + rdB + 6144u);
        // stage kt+1 into the other buffer (disjoint from all current reads)
        if (kt < 15) {
            STG(gxa + ko,                     nb          + ldst);
            STG(gxa +  64 * (size_t)IN + ko,  nb + 8192u  + ldst);
            STG(gxa + 128 * (size_t)IN + ko,  nb + 16384u + ldst);
            STG(gxa + 192 * (size_t)IN + ko,  nb + 24576u + ldst);
            STG(gwb + ko,                     nb + 32768u + ldst);
            STG(gwb +  64 * (size_t)IN + ko,  nb + 40960u + ldst);
            STG(gwb + 128 * (size_t)IN + ko,  nb + 49152u + ldst);
            STG(gwb + 192 * (size_t)IN + ko,  nb + 57344u + ldst);
        }
        asm volatile("s_waitcnt lgkmcnt(0)" ::: "memory");
        __builtin_amdgcn_sched_barrier(0);
        __builtin_amdgcn_s_setprio(1);
        #pragma unroll
        for (int j = 0; j < 4; j++)
            #pragma unroll
            for (int i = 0; i < 4; i++) { MFMA1(af[i], bf[j], acc[i][j]); }
        __builtin_amdgcn_s_setprio(0);
        __builtin_amdgcn_sched_barrier(0);   // keep afH reads BELOW cluster 1 (reg reuse)
        // reads for cluster 2: A rows wrow+64..wrow+127 (reuse af regs)
        RD8(af[0], cb + rdA + 8192u);
        RD8(af[1], cb + rdA + 10240u);
        RD8(af[2], cb + rdA + 12288u);
        RD8(af[3], cb + rdA + 14336u);
        asm volatile("s_waitcnt lgkmcnt(0)" ::: "memory");
        __builtin_amdgcn_sched_barrier(0);
        __builtin_amdgcn_s_setprio(1);
        #pragma unroll
        for (int j = 0; j < 4; j++)
            #pragma unroll
            for (int i = 0; i < 4; i++) { MFMA1(af[i], bf[j], acc[4 + i][j]); }
        __builtin_amdgcn_s_setprio(0);
        // single sync point: my reads of buf[kt] done (lgkm above), my stages
        // of buf[kt+1] landed (vmcnt), then barrier -> all waves agree.
        if (kt < 15) {
            asm volatile("s_waitcnt vmcnt(0)" ::: "memory");
            __builtin_amdgcn_s_barrier();
        }
        cb = nb;
    }

    // epilogue: per-row top-4 (u32 keys) over this wave's 64 columns
    const int group = blockIdx.x * 4 + (w & 3);   // 64-col group id, 0..127
    #pragma unroll
    for (int i = 0; i < 8; i++) {
        #pragma unroll
        for (int r = 0; r < 4; r++) {
            u32 k0 = (fkey(acc[i][0][r]) & 0xFFFFFFC0u) | (0u << 4) | (u32)m;
            u32 k1 = (fkey(acc[i][1][r]) & 0xFFFFFFC0u) | (1u << 4) | (u32)m;
            u32 k2 = (fkey(acc[i][2][r]) & 0xFFFFFFC0u) | (2u << 4) | (u32)m;
            u32 k3 = (fkey(acc[i][3][r]) & 0xFFFFFFC0u) | (3u << 4) | (u32)m;
            // sort 4 desc
            ce32(k0, k1); ce32(k2, k3); ce32(k0, k2); ce32(k1, k3); ce32(k1, k2);
            // butterfly top-4 merge over the 16 lanes sharing this row
            #pragma unroll
            for (int off = 1; off < 16; off <<= 1) {
                u32 b0 = __shfl_xor(k0, off, 64);
                u32 b1 = __shfl_xor(k1, off, 64);
                u32 b2 = __shfl_xor(k2, off, 64);
                u32 b3 = __shfl_xor(k3, off, 64);
                u32 t0 = k0 > b3 ? k0 : b3;    // bitonic keep-max
                u32 t1 = k1 > b2 ? k1 : b2;
                u32 t2 = k2 > b1 ? k2 : b1;
                u32 t3 = k3 > b0 ? k3 : b0;
                ce32(t0, t2); ce32(t1, t3); ce32(t0, t1); ce32(t2, t3);
                k0 = t0; k1 = t1; k2 = t2; k3 = t3;
            }
            if (m == 0) {
                const int grow = bm + wrow + i * 16 + q * 4 + r;
                uint4 v; v.x = k0; v.y = k1; v.z = k2; v.w = k3;
                *(uint4*)&topk[(size_t)grow * 512 + group * 4] = v;
            }
        }
    }
}

// ---------- scan: one WAVE per row; ballot compaction; exact rescore; gather ----------
__global__ __launch_bounds__(256) void scan_kernel(
    const u32* __restrict__ topk,
    const float* __restrict__ x, const float* __restrict__ Wk,
    const float* __restrict__ WgT, float* __restrict__ out)
{
    __shared__ u16 cand[4][48];
    const int wv   = threadIdx.x >> 6;
    const int lane = threadIdx.x & 63;
    const int row  = blockIdx.x * 4 + wv;

    const uint4* tp = (const uint4*)(topk + (size_t)row * 512);
    uint4 v0 = tp[lane];        // group = lane
    uint4 v1 = tp[lane + 64];   // group = lane + 64

    // row max (u32 keys are value-ordered; id bits only break near-ties)
    u32 mx = v0.x > v1.x ? v0.x : v1.x;   // slot 0 of each uint4 is its group's max
    #pragma unroll
    for (int off = 1; off < 64; off <<= 1) {
        u32 o = __shfl_xor(mx, off, 64);
        if (o > mx) mx = o;
    }
    const float thr = unfkey(mx & 0xFFFFFFC0u) - 12.0f;

    // ballot-compact in-window candidates into per-wave LDS (no atomics)
    int base = 0;
    const u32 ks[8] = {v0.x, v0.y, v0.z, v0.w, v1.x, v1.y, v1.z, v1.w};
    #pragma unroll
    for (int s = 0; s < 8; s++) {
        const int group = (s < 4) ? lane : (lane + 64);
        const u32 key = ks[s];
        const bool in = unfkey(key & 0xFFFFFFC0u) >= thr;
        const u64 msk = __ballot(in);
        if (in) {
            int rnk = base + __popcll(msk & ((1ull << lane) - 1ull));
            if (rnk < 48)
                cand[wv][rnk] = (u16)(group * 64 + (int)((key >> 4) & 3u) * 16 + (int)(key & 15u));
        }
        base += __popcll(msk);
    }
    const int n = min(base, 48);
    __builtin_amdgcn_wave_barrier();   // keep compiler from sinking LDS reads above writes

    int col;
    if (n <= 1) {
        col = cand[wv][0];   // the max itself is always in-window
    } else {
        // exact fp32 rescore, whole wave per candidate
        const float4* xr = (const float4*)(x + (size_t)row * IN);
        float4 a[8];
        #pragma unroll
        for (int p = 0; p < 8; p++) a[p] = xr[p * 64 + lane];
        u64 best = 0ull;
        for (int c = 0; c < n; c++) {
            const int h = cand[wv][c];
            const float4* wr = (const float4*)(Wk + (size_t)h * IN);
            float s = 0.f;
            #pragma unroll
            for (int p = 0; p < 8; p++) {
                float4 b = wr[p * 64 + lane];
                s += a[p].x * b.x + a[p].y * b.y + a[p].z * b.z + a[p].w * b.w;
            }
            #pragma unroll
            for (int off = 1; off < 64; off <<= 1) s += __shfl_xor(s, off, 64);
            // s identical on all lanes; track best on all lanes (no broadcast needed)
            u64 key = ((u64)fkey(s) << 32) | (u64)(0x1FFFu - (u32)h);  // smaller col wins ties
            if (key > best) best = key;
        }
        col = 0x1FFF - (int)(best & 0xFFFFu);
    }

    // gather: out[row, :] = WgT[col, :]   (both rows 16B-aligned: 1000*4 = 4000 B)
    const float4* src = (const float4*)(WgT + (size_t)col * NCLS);
    float4* dst = (float4*)(out + (size_t)row * NCLS);
    for (int t = lane; t < NCLS / 4; t += 64) dst[t] = src[t];
}

// ---------- round-1 fp32 fallback (used only if ws too small) ----------
__global__ void init_ws_kernel(u64* rowkey) {
    int i = blockIdx.x * blockDim.x + threadIdx.x;
    if (i < BATCH) rowkey[i] = 0ULL;
}

__global__ __launch_bounds__(256) void gemm_argmax_kernel(
    const float* __restrict__ x, const float* __restrict__ Wk,
    u64* __restrict__ rowkey)
{
    __shared__ __align__(16) float As[32 * 64];
    __shared__ __align__(16) float Bs[32 * 64];
    const int tid = threadIdx.x;
    const int bm = blockIdx.y * 64, bn = blockIdx.x * 64;
    const int tx = tid & 15, ty = tid >> 4;
    float acc[4][4];
    #pragma unroll
    for (int i = 0; i < 4; i++)
        #pragma unroll
        for (int j = 0; j < 4; j++) acc[i][j] = 0.f;
    const int r0 = tid >> 3, q0 = tid & 7;
    const int r1 = (tid + 256) >> 3, q1 = (tid + 256) & 7;
    const float* xA0 = &x[(size_t)(bm + r0) * IN + q0 * 4];
    const float* xA1 = &x[(size_t)(bm + r1) * IN + q1 * 4];
    const float* wB0 = &Wk[(size_t)(bn + r0) * IN + q0 * 4];
    const float* wB1 = &Wk[(size_t)(bn + r1) * IN + q1 * 4];
    for (int k0 = 0; k0 < IN; k0 += 32) {
        float4 a0 = *(const float4*)(xA0 + k0);
        float4 a1 = *(const float4*)(xA1 + k0);
        float4 b0 = *(const float4*)(wB0 + k0);
        float4 b1 = *(const float4*)(wB1 + k0);
        __syncthreads();
        As[(q0 * 4 + 0) * 64 + r0] = a0.x; As[(q0 * 4 + 1) * 64 + r0] = a0.y;
        As[(q0 * 4 + 2) * 64 + r0] = a0.z; As[(q0 * 4 + 3) * 64 + r0] = a0.w;
        As[(q1 * 4 + 0) * 64 + r1] = a1.x; As[(q1 * 4 + 1) * 64 + r1] = a1.y;
        As[(q1 * 4 + 2) * 64 + r1] = a1.z; As[(q1 * 4 + 3) * 64 + r1] = a1.w;
        Bs[(q0 * 4 + 0) * 64 + r0] = b0.x; Bs[(q0 * 4 + 1) * 64 + r0] = b0.y;
        Bs[(q0 * 4 + 2) * 64 + r0] = b0.z; Bs[(q0 * 4 + 3) * 64 + r0] = b0.w;
        Bs[(q1 * 4 + 0) * 64 + r1] = b1.x; Bs[(q1 * 4 + 1) * 64 + r1] = b1.y;
        Bs[(q1 * 4 + 2) * 64 + r1] = b1.z; Bs[(q1 * 4 + 3) * 64 + r1] = b1.w;
        __syncthreads();
        #pragma unroll
        for (int k = 0; k < 32; k++) {
            float4 av = *(const float4*)&As[k * 64 + ty * 4];
            float4 bv = *(const float4*)&Bs[k * 64 + tx * 4];
            acc[0][0] += av.x * bv.x; acc[0][1] += av.x * bv.y;
            acc[0][2] += av.x * bv.z; acc[0][3] += av.x * bv.w;
            acc[1][0] += av.y * bv.x; acc[1][1] += av.y * bv.y;
            acc[1][2] += av.y * bv.z; acc[1][3] += av.y * bv.w;
            acc[2][0] += av.z * bv.x; acc[2][1] += av.z * bv.y;
            acc[2][2] += av.z * bv.z; acc[2][3] += av.z * bv.w;
            acc[3][0] += av.w * bv.x; acc[3][1] += av.w * bv.y;
            acc[3][2] += av.w * bv.z; acc[3][3] += av.w * bv.w;
        }
    }
    #pragma unroll
    for (int i = 0; i < 4; i++) {
        const int row = bm + ty * 4 + i;
        u64 best = 0ULL;
        #pragma unroll
        for (int j = 0; j < 4; j++) {
            const int col = bn + tx * 4 + j;
            u64 p = ((u64)fkey(acc[i][j]) << 32) | (u64)(0x1FFFu - (unsigned)col);
            if (p > best) best = p;
        }
        #pragma unroll
        for (int off = 1; off < 16; off <<= 1) {
            u64 other = __shfl_xor(best, off, 64);
            if (other > best) best = other;
        }
        if (tx == 0) atomicMax(&rowkey[row], best);
    }
}

__global__ __launch_bounds__(256) void gather_kernel(
    const u64* __restrict__ rowkey, const float* __restrict__ Wg,
    float* __restrict__ out)
{
    const int b = blockIdx.y;
    const int c = blockIdx.x * 256 + threadIdx.x;
    if (c >= NCLS) return;
    const int col = 0x1FFF - (int)(rowkey[b] & 0xFFFFFFFFu);
    out[(size_t)b * NCLS + c] = Wg[(size_t)c * HID + col];
}

// ---------- launch ----------
extern "C" void kernel_launch(void* const* d_in, const int* in_sizes, int n_in,
                              void* d_out, int out_size, void* d_ws, size_t ws_size,
                              hipStream_t stream) {
    const float* x  = (const float*)d_in[0];
    const float* Wk = (const float*)d_in[1];
    const float* Wg = (const float*)d_in[2];
    float* out = (float*)d_out;
    char* ws = (char*)d_ws;

    if (ws_size >= TOTAL_FULL) {
        u32* topk  = (u32*)(ws + OFF_TOPK);
        u8*  x8    = (u8*)(ws + OFF_X8);
        u8*  wk8   = (u8*)(ws + OFF_WK8);
        float* WgT = (float*)(ws + OFF_WGT);

        hipLaunchKernelGGL(prep_kernel, dim3(1024 + 8192), dim3(256), 0, stream,
                           x, Wk, Wg, x8, wk8, WgT);
        hipLaunchKernelGGL(mfma_fp8_gemm_kernel, dim3(HID / 256, BATCH / 256), dim3(512), 0, stream,
                           x8, wk8, topk);
        hipLaunchKernelGGL(scan_kernel, dim3(BATCH / 4), dim3(256), 0, stream,
                           topk, x, Wk, WgT, out);
    } else {
        u64* rowkey = (u64*)(ws + OFF_ROWKEY);
        hipLaunchKernelGGL(init_ws_kernel, dim3(16), dim3(256), 0, stream, rowkey);
        hipLaunchKernelGGL(gemm_argmax_kernel, dim3(HID / 64, BATCH / 64), dim3(256), 0, stream,
                           x, Wk, rowkey);
        hipLaunchKernelGGL(gather_kernel, dim3(4, BATCH), dim3(256), 0, stream,
                           rowkey, Wg, out);
    }
}